// Round 3
// baseline (7475.132 us; speedup 1.0000x reference)
//
#include <hip/hip_runtime.h>

// Fused per-batch graph encoder, v3.
// v2 + W-cache actually pinned in VGPRs (asm "+v" keep-alive), double-buffered
// gather slot. One 512-thread block (8 waves) per batch element, 2 blocks/CU.

#define BLK 512
#define NHX 19
#define NVX 54
#define NED 72
#define TF  32
#define HD  64
#define NROWS 145   // 19 + 54 + 72
#define VBASE 19
#define EBASE 73

__device__ __forceinline__ float wsum64(float v){
#pragma unroll
  for (int m = 32; m >= 1; m >>= 1) v += __shfl_xor(v, m, 64);
  return v;
}

__device__ __forceinline__ float ln_relu(float y, float g, float be){
  float mu  = wsum64(y) * (1.f/64.f);
  float d   = y - mu;
  float var = wsum64(d*d) * (1.f/64.f);
  return fmaxf(fmaf(d * rsqrtf(var + 1e-5f), g, be), 0.f);
}

// 64-long dot; x broadcast from LDS as float4, w pinned in registers.
__device__ __forceinline__ float dot64(const float* x, const float* w){
  float a0=0.f, a1=0.f, a2=0.f, a3=0.f;
  const float4* x4 = (const float4*)x;
#pragma unroll
  for (int q = 0; q < 16; ++q){
    float4 v = x4[q];
    a0 = fmaf(v.x, w[4*q+0], a0);
    a1 = fmaf(v.y, w[4*q+1], a1);
    a2 = fmaf(v.z, w[4*q+2], a2);
    a3 = fmaf(v.w, w[4*q+3], a3);
  }
  return (a0+a1) + (a2+a3);
}

__device__ __forceinline__ float dot32(const float* x, const float* w){
  float a0=0.f, a1=0.f, a2=0.f, a3=0.f;
  const float4* x4 = (const float4*)x;
#pragma unroll
  for (int q = 0; q < 8; ++q){
    float4 v = x4[q];
    a0 = fmaf(v.x, w[4*q+0], a0);
    a1 = fmaf(v.y, w[4*q+1], a1);
    a2 = fmaf(v.z, w[4*q+2], a2);
    a3 = fmaf(v.w, w[4*q+3], a3);
  }
  return (a0+a1) + (a2+a3);
}

__device__ __forceinline__ void gather_row(
    const float* s_acts, const int* __restrict__ idx, int deg,
    int src_base, int row, int lane, float* dst)
{
  float s = 0.f; int c = 0;
  for (int j = 0; j < deg; ++j){
    int ix = idx[row*deg + j];
    if (ix >= 0){ s += s_acts[(src_base + ix)*HD + lane]; c++; }
  }
  dst[lane] = s / (float)(c > 0 ? c : 1);
}

// One (W-segment, row-range) task: partial 64-dot for rows [r0,r1),
// atomically accumulated into s_acc. idx==nullptr -> self rows.
__device__ __forceinline__ void run_task(
    const float* __restrict__ Wseg,
    const float* s_acts, float* s_acc, float* slot0, float* slot1,
    const int* __restrict__ idx, int deg, int src_base,
    int self_base, int acc_base, int r0, int r1, int lane)
{
  float wreg[64];
#pragma unroll
  for (int k = 0; k < 64; ++k) wreg[k] = Wseg[k*HD + lane];
  // Pin the W cache in VGPRs: without this the compiler rematerializes the
  // loads inside the row loop (observed: VGPR_Count=56, L2-latency-bound).
#pragma unroll
  for (int k = 0; k < 64; ++k) asm volatile("" : "+v"(wreg[k]));

  if (idx == nullptr){
    for (int row = r0; row < r1; ++row){
      float v = dot64(s_acts + (self_base + row)*HD, wreg);
      atomicAdd(&s_acc[(acc_base + row)*HD + lane], v);
    }
  } else {
    gather_row(s_acts, idx, deg, src_base, r0, lane, slot0);
    __builtin_amdgcn_wave_barrier();
    asm volatile("" ::: "memory");
    for (int row = r0; row < r1; ++row){
      float* cur = ((row - r0) & 1) ? slot1 : slot0;
      float* nxt = ((row - r0) & 1) ? slot0 : slot1;
      if (row + 1 < r1) gather_row(s_acts, idx, deg, src_base, row + 1, lane, nxt);
      float v = dot64(cur, wreg);
      __builtin_amdgcn_wave_barrier();
      asm volatile("" ::: "memory");
      atomicAdd(&s_acc[(acc_base + row)*HD + lane], v);
    }
  }
}

__global__ __launch_bounds__(BLK, 4)
void graph_enc_kernel(
    const float* __restrict__ tile,
    const int* __restrict__ h2v, const int* __restrict__ v2h,
    const int* __restrict__ e2v, const int* __restrict__ v2e,
    const float* __restrict__ hinW, const float* __restrict__ hinb,
    const float* __restrict__ hing, const float* __restrict__ hinbe,
    const float* __restrict__ vinW, const float* __restrict__ vinb,
    const float* __restrict__ ving, const float* __restrict__ vinbe,
    const float* __restrict__ einW, const float* __restrict__ einb,
    const float* __restrict__ eing, const float* __restrict__ einbe,
    const float* __restrict__ huW, const float* __restrict__ hub,
    const float* __restrict__ hug, const float* __restrict__ hube,
    const float* __restrict__ vuW, const float* __restrict__ vub,
    const float* __restrict__ vug, const float* __restrict__ vube,
    const float* __restrict__ euW, const float* __restrict__ eub,
    const float* __restrict__ eug, const float* __restrict__ eube,
    const float* __restrict__ roW, const float* __restrict__ rob,
    const float* __restrict__ rog, const float* __restrict__ robe,
    float* __restrict__ out)
{
  // 20384 floats = 81,536 B -> still 2 blocks/CU (<= 81,920 B)
  __shared__ __align__(16) float sm[20384];
  float* s_acts = sm;            // 145*64 = 9280
  float* s_acc  = sm + 9280;     // 145*64 = 9280 (overlaid: vraw/eraw in stage 0)
  float* s_tile = sm + 18560;    // 19*32 = 608
  float* s_pool = sm + 19168;    // 192
  float* s_slot = sm + 19360;    // 8*2*64 = 1024
  float* s_vraw = s_acc;         // 54*32 = 1728
  float* s_eraw = s_acc + 1728;  // 72*32 = 2304

  const int b    = blockIdx.x;
  const int t    = threadIdx.x;
  const int lane = t & 63;
  const int wv   = t >> 6;
  float* slot0 = s_slot + wv*2*HD;
  float* slot1 = slot0 + HD;

  // ---- stage tile features ----
  const float* tsrc = tile + (size_t)b * (NHX*TF);
  for (int i = t; i < NHX*TF; i += BLK) s_tile[i] = tsrc[i];
  __syncthreads();

  // ---- vertex_raw / edge_raw ----
  for (int e = t; e < NVX*TF; e += BLK){
    int v = e >> 5, k = e & 31;
    float s = 0.f; int c = 0;
#pragma unroll
    for (int j = 0; j < 3; ++j){
      int ix = v2h[v*3+j];
      if (ix >= 0){ s += s_tile[ix*TF + k]; c++; }
    }
    s_vraw[e] = s / (float)(c > 0 ? c : 1);
  }
  __syncthreads();
  for (int e = t; e < NED*TF; e += BLK){
    int ed = e >> 5, k = e & 31;
    float s = 0.f; int c = 0;
#pragma unroll
    for (int j = 0; j < 2; ++j){
      int ix = e2v[ed*2+j];
      if (ix >= 0){ s += s_vraw[ix*TF + k]; c++; }
    }
    s_eraw[e] = s / (float)(c > 0 ? c : 1);
  }
  __syncthreads();

  // ---- stage-0 input layers (K=32), direct LN, ~18 rows/wave ----
  {
    const float *Wp, *bp, *gp, *bep, *xs; int r0, r1, obase;
    if (wv == 0)      { Wp=hinW; bp=hinb; gp=hing; bep=hinbe; xs=s_tile; r0=0;          r1=NHX;   obase=0;     }
    else if (wv <= 3) { Wp=vinW; bp=vinb; gp=ving; bep=vinbe; xs=s_vraw; r0=(wv-1)*18;  r1=r0+18; obase=VBASE; }
    else              { Wp=einW; bp=einb; gp=eing; bep=einbe; xs=s_eraw; r0=(wv-4)*18;  r1=r0+18; obase=EBASE; }
    float wreg[32];
#pragma unroll
    for (int k = 0; k < 32; ++k) wreg[k] = Wp[k*HD + lane];
#pragma unroll
    for (int k = 0; k < 32; ++k) asm volatile("" : "+v"(wreg[k]));
    float bv = bp[lane], gv = gp[lane], bev = bep[lane];
    for (int row = r0; row < r1; ++row){
      float v = bv + dot32(xs + row*TF, wreg);
      s_acts[(obase + row)*HD + lane] = ln_relu(v, gv, bev);
    }
  }
  __syncthreads();

  // ---- 2 message-passing rounds ----
  for (int r = 0; r < 2; ++r){
    for (int i = t; i < NROWS*HD; i += BLK) s_acc[i] = 0.f;
    __syncthreads();

    const float* huWr = huW + r*128*HD;
    const float* vuWr = vuW + r*192*HD;
    const float* euWr = euW + r*128*HD;

    // task phase: 344 row-segments balanced 39-44 per wave
    switch (wv){
      case 0:
        run_task(huWr,          s_acts, s_acc, slot0, slot1, nullptr, 0, 0,     0,     0,     0, 19, lane);
        run_task(huWr + 64*HD,  s_acts, s_acc, slot0, slot1, h2v,     6, VBASE, 0,     0,     0, 19, lane);
        run_task(euWr + 64*HD,  s_acts, s_acc, slot0, slot1, e2v,     2, VBASE, 0,     EBASE, 66, 72, lane);
        break;
      case 1:
        run_task(vuWr,          s_acts, s_acc, slot0, slot1, nullptr, 0, 0,     VBASE, VBASE, 0, 44, lane);
        break;
      case 2:
        run_task(vuWr + 64*HD,  s_acts, s_acc, slot0, slot1, v2h,     3, 0,     0,     VBASE, 0, 44, lane);
        break;
      case 3:
        run_task(vuWr + 128*HD, s_acts, s_acc, slot0, slot1, v2e,     3, EBASE, 0,     VBASE, 0, 44, lane);
        break;
      case 4:
        run_task(vuWr,          s_acts, s_acc, slot0, slot1, nullptr, 0, 0,     VBASE, VBASE, 44, 54, lane);
        run_task(euWr,          s_acts, s_acc, slot0, slot1, nullptr, 0, 0,     EBASE, EBASE, 0, 33, lane);
        break;
      case 5:
        run_task(vuWr + 64*HD,  s_acts, s_acc, slot0, slot1, v2h,     3, 0,     0,     VBASE, 44, 54, lane);
        run_task(euWr,          s_acts, s_acc, slot0, slot1, nullptr, 0, 0,     EBASE, EBASE, 33, 66, lane);
        break;
      case 6:
        run_task(vuWr + 128*HD, s_acts, s_acc, slot0, slot1, v2e,     3, EBASE, 0,     VBASE, 44, 54, lane);
        run_task(euWr + 64*HD,  s_acts, s_acc, slot0, slot1, e2v,     2, VBASE, 0,     EBASE, 0, 33, lane);
        break;
      case 7:
        run_task(euWr,          s_acts, s_acc, slot0, slot1, nullptr, 0, 0,     EBASE, EBASE, 66, 72, lane);
        run_task(euWr + 64*HD,  s_acts, s_acc, slot0, slot1, e2v,     2, VBASE, 0,     EBASE, 33, 66, lane);
        break;
    }
    __syncthreads();

    // reduce phase: bias + LN + relu, in-place into acts
    {
      int rr0 = wv*19, rr1 = rr0 + 19 < NROWS ? rr0 + 19 : NROWS;
      for (int row = rr0; row < rr1; ++row){
        const float *bp, *gp, *bep;
        if (row < VBASE)      { bp = hub + r*HD; gp = hug + r*HD; bep = hube + r*HD; }
        else if (row < EBASE) { bp = vub + r*HD; gp = vug + r*HD; bep = vube + r*HD; }
        else                  { bp = eub + r*HD; gp = eug + r*HD; bep = eube + r*HD; }
        float v = s_acc[row*HD + lane] + bp[lane];
        s_acts[row*HD + lane] = ln_relu(v, gp[lane], bep[lane]);
      }
    }
    __syncthreads();
  }

  // ---- pooling (t<192) + zero readout acc (t 192..255) ----
  if (t < 192){
    int c = t & 63, ty = t >> 6;
    float s = 0.f;
    if (ty == 0){
      for (int n = 0; n < NHX; ++n) s += s_acts[n*HD + c];
      s *= (1.f/(float)NHX);
    } else if (ty == 1){
      for (int n = 0; n < NVX; ++n) s += s_acts[(VBASE+n)*HD + c];
      s *= (1.f/(float)NVX);
    } else {
      for (int n = 0; n < NED; ++n) s += s_acts[(EBASE+n)*HD + c];
      s *= (1.f/(float)NED);
    }
    s_pool[t] = s;
  } else if (t < 256){
    s_acc[t - 192] = 0.f;
  }
  __syncthreads();

  // ---- readout: 3 waves each do one 64-segment of K=192 ----
  if (wv < 3){
    float wreg[64];
#pragma unroll
    for (int k = 0; k < 64; ++k) wreg[k] = roW[(wv*64 + k)*HD + lane];
#pragma unroll
    for (int k = 0; k < 64; ++k) asm volatile("" : "+v"(wreg[k]));
    float v = dot64(s_pool + wv*64, wreg);
    atomicAdd(&s_acc[lane], v);
  }
  __syncthreads();
  if (wv == 0){
    float v = s_acc[lane] + rob[lane];
    out[(size_t)b*HD + lane] = ln_relu(v, rog[lane], robe[lane]);
  }
}

extern "C" void kernel_launch(void* const* d_in, const int* in_sizes, int n_in,
                              void* d_out, int out_size, void* d_ws, size_t ws_size,
                              hipStream_t stream) {
  const float* tile = (const float*)d_in[0];
  const int* h2v  = (const int*)d_in[1];
  const int* v2h  = (const int*)d_in[2];
  const int* e2v  = (const int*)d_in[3];
  const int* v2e  = (const int*)d_in[4];
  const float* hinW = (const float*)d_in[5];
  const float* hinb = (const float*)d_in[6];
  const float* hing = (const float*)d_in[7];
  const float* hinbe= (const float*)d_in[8];
  const float* vinW = (const float*)d_in[9];
  const float* vinb = (const float*)d_in[10];
  const float* ving = (const float*)d_in[11];
  const float* vinbe= (const float*)d_in[12];
  const float* einW = (const float*)d_in[13];
  const float* einb = (const float*)d_in[14];
  const float* eing = (const float*)d_in[15];
  const float* einbe= (const float*)d_in[16];
  const float* huW  = (const float*)d_in[17];
  const float* hub  = (const float*)d_in[18];
  const float* hug  = (const float*)d_in[19];
  const float* hube = (const float*)d_in[20];
  const float* vuW  = (const float*)d_in[21];
  const float* vub  = (const float*)d_in[22];
  const float* vug  = (const float*)d_in[23];
  const float* vube = (const float*)d_in[24];
  const float* euW  = (const float*)d_in[25];
  const float* eub  = (const float*)d_in[26];
  const float* eug  = (const float*)d_in[27];
  const float* eube = (const float*)d_in[28];
  const float* roW  = (const float*)d_in[29];
  const float* rob  = (const float*)d_in[30];
  const float* rog  = (const float*)d_in[31];
  const float* robe = (const float*)d_in[32];
  float* out = (float*)d_out;

  int B = in_sizes[0] / (NHX*TF);   // 16384
  hipLaunchKernelGGL(graph_enc_kernel, dim3(B), dim3(BLK), 0, stream,
      tile, h2v, v2h, e2v, v2e,
      hinW, hinb, hing, hinbe,
      vinW, vinb, ving, vinbe,
      einW, einb, eing, einbe,
      huW, hub, hug, hube,
      vuW, vub, vug, vube,
      euW, eub, eug, eube,
      roW, rob, rog, robe,
      out);
}

// Round 4
// 3918.702 us; speedup vs baseline: 1.9076x; 1.9076x over previous
//
#include <hip/hip_runtime.h>

// Fused per-batch graph encoder, v4: MFMA bf16.
// 512 threads (8 waves) per batch element, 72KB LDS -> 2 blocks/CU.
// acts/gather buffers: bf16 in LDS, XOR-swizzled (chunk ^ (row&15)) so all
// ds_read_b64 fragment loads are bank-conflict-free. Each wave owns 1-2
// 16-row output tiles end-to-end: MFMA acc in regs -> 16-lane shfl LN ->
// bf16 writeback. vuW staged per round into LDS (bf16, transposed);
// huW/euW B-frags loaded from global (L2-hot).

#define BLK 512

typedef short v4s __attribute__((ext_vector_type(4)));
typedef short v8s __attribute__((ext_vector_type(8)));
typedef float v4f __attribute__((ext_vector_type(4)));

// byte offsets into the 73728-B shared block
#define ACTS    0              // 160 rows x 64 col bf16, stride 128, swz mask 15
#define GATA    20480          // 160 x 64 (h_from_v / v_from_h / e_from_v)
#define GATB    40960          // 64 x 64  (v_from_e)
#define WLDS    49152          // W^T: 64 n-rows x 192 k-cols bf16, stride 384
// stage-0 overlays (GATA/GATB regions are free until the rounds)
#define S0TILEF (GATA + 0)     // 19x32 f32, plain
#define S0VRAWF (GATA + 2432)  // 54x32 f32, plain
#define S0TILEB (GATA + 9344)  // 32x32 bf16, stride 64, swz mask 7
#define S0VRAWB (GATA + 11392) // 64x32 bf16
#define S0ERAWB (GATB + 0)     // 80x32 bf16
// post-round overlays (GATB free after last round)
#define POOLF   (GATB + 6144)  // 192 f32
#define RACC    (GATB + 6912)  // 64 f32

__device__ __forceinline__ unsigned short f2bf(float f){
  unsigned u = __float_as_uint(f);
  return (unsigned short)((u + 0x7fffu + ((u >> 16) & 1u)) >> 16);
}
__device__ __forceinline__ float bf2f(unsigned short h){
  return __uint_as_float(((unsigned)h) << 16);
}

__device__ __forceinline__ float red16(float v){
  v += __shfl_xor(v, 1, 64);
  v += __shfl_xor(v, 2, 64);
  v += __shfl_xor(v, 4, 64);
  v += __shfl_xor(v, 8, 64);
  return v;
}
__device__ __forceinline__ float red64(float v){
#pragma unroll
  for (int m = 32; m >= 1; m >>= 1) v += __shfl_xor(v, m, 64);
  return v;
}

__device__ __forceinline__ int swz_off(int base, int stride, int row, int col, int m){
  return base + row*stride + ((((col >> 2) ^ (row & m)) << 3) + ((col & 3) << 1));
}
__device__ __forceinline__ unsigned short lds_bf_read(const unsigned char* sm, int base, int stride, int row, int col, int m){
  return *(const unsigned short*)(sm + swz_off(base, stride, row, col, m));
}
__device__ __forceinline__ void lds_bf_write(unsigned char* sm, int base, int stride, int row, int col, int m, unsigned short v){
  *(unsigned short*)(sm + swz_off(base, stride, row, col, m)) = v;
}

// fragment: elems 0-3 = k-block [4*(l>>4), +4), elems 4-7 = +16. chunk cb = (kbase/4)+(l>>4).
__device__ __forceinline__ v8s load_frag(const unsigned char* sm, int base, int stride, int row, int cb, int m){
  v4s lo = *(const v4s*)(sm + base + row*stride + (((cb    ) ^ (row & m)) << 3));
  v4s hi = *(const v4s*)(sm + base + row*stride + (((cb + 4) ^ (row & m)) << 3));
  v8s r; r[0]=lo[0]; r[1]=lo[1]; r[2]=lo[2]; r[3]=lo[3]; r[4]=hi[0]; r[5]=hi[1]; r[6]=hi[2]; r[7]=hi[3];
  return r;
}

// B-fragment from global f32 W[K][64]: lane l elem j -> W[kbase + 16*(j>>2) + 4*(l>>4) + (j&3)][nt*16 + (l&15)]
__device__ __forceinline__ v8s load_bfrag_g(const float* __restrict__ W, int kbase, int nt, int lane){
  int n = nt*16 + (lane & 15);
  int g = (lane >> 4) << 2;
  const float* p = W + (size_t)(kbase + g)*64 + n;
  float f0 = p[0], f1 = p[64], f2 = p[128], f3 = p[192];
  const float* q = p + 1024;
  float f4 = q[0], f5 = q[64], f6 = q[128], f7 = q[192];
  v8s r;
  r[0]=(short)f2bf(f0); r[1]=(short)f2bf(f1); r[2]=(short)f2bf(f2); r[3]=(short)f2bf(f3);
  r[4]=(short)f2bf(f4); r[5]=(short)f2bf(f5); r[6]=(short)f2bf(f6); r[7]=(short)f2bf(f7);
  return r;
}

// TYPE: 0=hex 1=vtx 2=edge. S0: stage-0 (K=32 raw-feature GEMM).
template<int TYPE, bool S0>
__device__ __forceinline__ void tile_accum(const unsigned char* sm, int roff, int lane,
                                           const float* __restrict__ Wg, v4f acc[4])
{
  constexpr int NSEG = S0 ? 1 : (TYPE == 1 ? 6 : 4);
  constexpr int STR  = S0 ? 64 : 128;
  constexpr int MSK  = S0 ? 7  : 15;
  const int m15 = lane & 15, g = lane >> 4;
  v8s af[NSEG];
#pragma unroll
  for (int s = 0; s < NSEG; ++s){
    int buf, rb, kb;
    if constexpr (S0){
      buf = (TYPE==0 ? S0TILEB : (TYPE==1 ? S0VRAWB : S0ERAWB)); rb = 0; kb = 0;
    } else {
      kb = s & 1;
      int ab = (TYPE==0 ? 0 : (TYPE==1 ? 19 : 73));
      if (s < 2)      { buf = ACTS; rb = ab; }
      else if (s < 4) { buf = GATA; rb = ab; }
      else            { buf = GATB; rb = 0;  }
    }
    af[s] = load_frag(sm, buf, STR, rb + roff + m15, kb*8 + g, MSK);
  }
#pragma unroll
  for (int nt = 0; nt < 4; ++nt){
#pragma unroll
    for (int s = 0; s < NSEG; ++s){
      v8s bf;
      if constexpr (TYPE == 1 && !S0){
        bf = load_frag(sm, WLDS, 384, nt*16 + m15, s*8 + g, 15);
      } else {
        bf = load_bfrag_g(Wg, s*32, nt, lane);
      }
      acc[nt] = __builtin_amdgcn_mfma_f32_16x16x32_bf16(af[s], bf, acc[nt], 0, 0, 0);
    }
  }
}

// LN+ReLU a 16-row tile held in acc[4] (C layout col=l&15, row=4*(l>>4)+q), write bf16 acts.
__device__ __forceinline__ void tile_ln_store(unsigned char* sm, int typeRow0, int Mv, int roff, int lane,
    const float* __restrict__ bp, const float* __restrict__ gp, const float* __restrict__ bep, v4f acc[4])
{
  int c0 = lane & 15, g4 = (lane >> 4) << 2;
  float bb[4], gg[4], ee[4];
#pragma unroll
  for (int nt = 0; nt < 4; ++nt){
    int col = nt*16 + c0;
    bb[nt] = bp[col]; gg[nt] = gp[col]; ee[nt] = bep[col];
  }
#pragma unroll
  for (int nt = 0; nt < 4; ++nt)
#pragma unroll
    for (int q = 0; q < 4; ++q) acc[nt][q] += bb[nt];
#pragma unroll
  for (int q = 0; q < 4; ++q){
    float s  = acc[0][q] + acc[1][q] + acc[2][q] + acc[3][q];
    float mu = red16(s) * 0.015625f;
    float d0 = acc[0][q]-mu, d1 = acc[1][q]-mu, d2 = acc[2][q]-mu, d3 = acc[3][q]-mu;
    float var = red16(d0*d0 + d1*d1 + d2*d2 + d3*d3) * 0.015625f;
    float rs = rsqrtf(var + 1e-5f);
    int row = roff + g4 + q;
    if (row < Mv){
      float y0 = fmaxf(fmaf(d0*rs, gg[0], ee[0]), 0.f);
      float y1 = fmaxf(fmaf(d1*rs, gg[1], ee[1]), 0.f);
      float y2 = fmaxf(fmaf(d2*rs, gg[2], ee[2]), 0.f);
      float y3 = fmaxf(fmaf(d3*rs, gg[3], ee[3]), 0.f);
      lds_bf_write(sm, ACTS, 128, typeRow0+row,  0+c0, 15, f2bf(y0));
      lds_bf_write(sm, ACTS, 128, typeRow0+row, 16+c0, 15, f2bf(y1));
      lds_bf_write(sm, ACTS, 128, typeRow0+row, 32+c0, 15, f2bf(y2));
      lds_bf_write(sm, ACTS, 128, typeRow0+row, 48+c0, 15, f2bf(y3));
    }
  }
}

__global__ __launch_bounds__(BLK, 4)
void graph_enc_kernel(
    const float* __restrict__ tile,
    const int* __restrict__ h2v, const int* __restrict__ v2h,
    const int* __restrict__ e2v, const int* __restrict__ v2e,
    const float* __restrict__ hinW, const float* __restrict__ hinb,
    const float* __restrict__ hing, const float* __restrict__ hinbe,
    const float* __restrict__ vinW, const float* __restrict__ vinb,
    const float* __restrict__ ving, const float* __restrict__ vinbe,
    const float* __restrict__ einW, const float* __restrict__ einb,
    const float* __restrict__ eing, const float* __restrict__ einbe,
    const float* __restrict__ huW, const float* __restrict__ hub,
    const float* __restrict__ hug, const float* __restrict__ hube,
    const float* __restrict__ vuW, const float* __restrict__ vub,
    const float* __restrict__ vug, const float* __restrict__ vube,
    const float* __restrict__ euW, const float* __restrict__ eub,
    const float* __restrict__ eug, const float* __restrict__ eube,
    const float* __restrict__ roW, const float* __restrict__ rob,
    const float* __restrict__ rog, const float* __restrict__ robe,
    float* __restrict__ out)
{
  __shared__ __align__(16) unsigned char sm[73728];
  const int b = blockIdx.x, t = threadIdx.x, lane = t & 63, wv = t >> 6;

  // ---- P0: stage tile features (f32 plain + bf16 swizzled) ----
  const float* tsrc = tile + (size_t)b * 608;
  float* tilef = (float*)(sm + S0TILEF);
  for (int i = t; i < 608; i += BLK){
    float f = tsrc[i];
    tilef[i] = f;
    lds_bf_write(sm, S0TILEB, 64, i >> 5, i & 31, 7, f2bf(f));
  }
  __syncthreads();
  // ---- P1: vertex_raw ----
  {
    float* vrawf = (float*)(sm + S0VRAWF);
    int hr = t >> 5, c = t & 31;
    for (int v = hr; v < 54; v += 16){
      float s = 0.f; int cnt = 0;
#pragma unroll
      for (int j = 0; j < 3; ++j){ int ix = v2h[v*3+j]; if (ix >= 0){ s += tilef[ix*32 + c]; cnt++; } }
      float mval = s / (float)(cnt > 0 ? cnt : 1);
      vrawf[v*32 + c] = mval;
      lds_bf_write(sm, S0VRAWB, 64, v, c, 7, f2bf(mval));
    }
  }
  __syncthreads();
  // ---- P2: edge_raw ----
  {
    const float* vrawf = (const float*)(sm + S0VRAWF);
    int hr = t >> 5, c = t & 31;
    for (int e = hr; e < 72; e += 16){
      float s = 0.f; int cnt = 0;
#pragma unroll
      for (int j = 0; j < 2; ++j){ int ix = e2v[e*2+j]; if (ix >= 0){ s += vrawf[ix*32 + c]; cnt++; } }
      float mval = s / (float)(cnt > 0 ? cnt : 1);
      lds_bf_write(sm, S0ERAWB, 64, e, c, 7, f2bf(mval));
    }
  }
  __syncthreads();

  v4f z; z[0]=0.f; z[1]=0.f; z[2]=0.f; z[3]=0.f;

  // ---- P3: stage-0 GEMMs (K=32) + LN ----
  {
    v4f a0[4] = {z,z,z,z}, a1[4] = {z,z,z,z};
    switch (wv){
      case 0: tile_accum<0,true>(sm, 0,lane,hinW,a0); tile_accum<0,true>(sm,16,lane,hinW,a1); break;
      case 1: tile_accum<1,true>(sm, 0,lane,vinW,a0); break;
      case 2: tile_accum<1,true>(sm,16,lane,vinW,a0); break;
      case 3: tile_accum<1,true>(sm,32,lane,vinW,a0); break;
      case 4: tile_accum<1,true>(sm,48,lane,vinW,a0); break;
      case 5: tile_accum<2,true>(sm, 0,lane,einW,a0); tile_accum<2,true>(sm,64,lane,einW,a1); break;
      case 6: tile_accum<2,true>(sm,16,lane,einW,a0); tile_accum<2,true>(sm,48,lane,einW,a1); break;
      case 7: tile_accum<2,true>(sm,32,lane,einW,a0); break;
    }
    __syncthreads();
    switch (wv){
      case 0: tile_ln_store(sm, 0,19, 0,lane,hinb,hing,hinbe,a0); tile_ln_store(sm, 0,19,16,lane,hinb,hing,hinbe,a1); break;
      case 1: tile_ln_store(sm,19,54, 0,lane,vinb,ving,vinbe,a0); break;
      case 2: tile_ln_store(sm,19,54,16,lane,vinb,ving,vinbe,a0); break;
      case 3: tile_ln_store(sm,19,54,32,lane,vinb,ving,vinbe,a0); break;
      case 4: tile_ln_store(sm,19,54,48,lane,vinb,ving,vinbe,a0); break;
      case 5: tile_ln_store(sm,73,72, 0,lane,einb,eing,einbe,a0); tile_ln_store(sm,73,72,64,lane,einb,eing,einbe,a1); break;
      case 6: tile_ln_store(sm,73,72,16,lane,einb,eing,einbe,a0); tile_ln_store(sm,73,72,48,lane,einb,eing,einbe,a1); break;
      case 7: tile_ln_store(sm,73,72,32,lane,einb,eing,einbe,a0); break;
    }
  }
  __syncthreads();

  // ---- 2 message-passing rounds ----
  for (int r = 0; r < 2; ++r){
    // P4a: stage vuW^T -> WLDS (bf16, swizzled)
    const float* vuWr = vuW + r*12288;
    for (int e = t; e < 12288; e += BLK){
      int k = e >> 6, n = e & 63;
      lds_bf_write(sm, WLDS, 384, n, k, 15, f2bf(vuWr[e]));
    }
    // P4b: gathers (199 rows, wave-strided) from old acts
    for (int gid = wv; gid < 199; gid += 8){
      const int* idx; int deg, srcB, dbase, drow;
      if (gid < 19)      { idx = h2v + gid*6;        deg = 6; srcB = 19; dbase = GATA; drow = gid; }
      else if (gid < 73) { int v = gid-19;  idx = v2h + v*3; deg = 3; srcB = 0;  dbase = GATA; drow = 19+v; }
      else if (gid < 145){ int e = gid-73;  idx = e2v + e*2; deg = 2; srcB = 19; dbase = GATA; drow = 73+e; }
      else               { int v = gid-145; idx = v2e + v*3; deg = 3; srcB = 73; dbase = GATB; drow = v; }
      float s = 0.f; int cnt = 0;
      for (int j = 0; j < deg; ++j){
        int ix = idx[j];
        if (ix >= 0){ s += bf2f(lds_bf_read(sm, ACTS, 128, srcB+ix, lane, 15)); cnt++; }
      }
      float mval = s / (float)(cnt > 0 ? cnt : 1);
      lds_bf_write(sm, dbase, 128, drow, lane, 15, f2bf(mval));
    }
    __syncthreads();
    // P5: GEMM accumulate (reads old acts + gathers; no LDS writes)
    const float* huWr = huW + r*8192;
    const float* euWr = euW + r*8192;
    v4f a0[4] = {z,z,z,z}, a1[4] = {z,z,z,z};
    switch (wv){
      case 0: tile_accum<0,false>(sm, 0,lane,huWr,a0); tile_accum<0,false>(sm,16,lane,huWr,a1); break;
      case 1: tile_accum<1,false>(sm, 0,lane,huWr,a0); break;
      case 2: tile_accum<1,false>(sm,16,lane,huWr,a0); break;
      case 3: tile_accum<1,false>(sm,32,lane,huWr,a0); break;
      case 4: tile_accum<1,false>(sm,48,lane,huWr,a0); break;
      case 5: tile_accum<2,false>(sm, 0,lane,euWr,a0); tile_accum<2,false>(sm,64,lane,euWr,a1); break;
      case 6: tile_accum<2,false>(sm,16,lane,euWr,a0); tile_accum<2,false>(sm,48,lane,euWr,a1); break;
      case 7: tile_accum<2,false>(sm,32,lane,euWr,a0); break;
    }
    __syncthreads();
    // P6: LN + writeback
    const float *hub_r = hub + r*64, *hug_r = hug + r*64, *hube_r = hube + r*64;
    const float *vub_r = vub + r*64, *vug_r = vug + r*64, *vube_r = vube + r*64;
    const float *eub_r = eub + r*64, *eug_r = eug + r*64, *eube_r = eube + r*64;
    switch (wv){
      case 0: tile_ln_store(sm, 0,19, 0,lane,hub_r,hug_r,hube_r,a0); tile_ln_store(sm, 0,19,16,lane,hub_r,hug_r,hube_r,a1); break;
      case 1: tile_ln_store(sm,19,54, 0,lane,vub_r,vug_r,vube_r,a0); break;
      case 2: tile_ln_store(sm,19,54,16,lane,vub_r,vug_r,vube_r,a0); break;
      case 3: tile_ln_store(sm,19,54,32,lane,vub_r,vug_r,vube_r,a0); break;
      case 4: tile_ln_store(sm,19,54,48,lane,vub_r,vug_r,vube_r,a0); break;
      case 5: tile_ln_store(sm,73,72, 0,lane,eub_r,eug_r,eube_r,a0); tile_ln_store(sm,73,72,64,lane,eub_r,eug_r,eube_r,a1); break;
      case 6: tile_ln_store(sm,73,72,16,lane,eub_r,eug_r,eube_r,a0); tile_ln_store(sm,73,72,48,lane,eub_r,eug_r,eube_r,a1); break;
      case 7: tile_ln_store(sm,73,72,32,lane,eub_r,eug_r,eube_r,a0); break;
    }
    __syncthreads();
  }

  // ---- P7: pooling (waves 0-2) + zero readout acc (wave 3) ----
  if (wv < 3){
    int R  = (wv == 0 ? 19 : (wv == 1 ? 54 : 72));
    int B0 = (wv == 0 ? 0  : (wv == 1 ? 19 : 73));
    float s = 0.f;
    for (int n = 0; n < R; ++n) s += bf2f(lds_bf_read(sm, ACTS, 128, B0+n, lane, 15));
    ((float*)(sm + POOLF))[wv*64 + lane] = s / (float)R;
  } else if (wv == 3){
    ((float*)(sm + RACC))[lane] = 0.f;
  }
  __syncthreads();
  // ---- P8: readout partials (waves 0-3, 48 K each) ----
  if (wv < 4){
    const float* pool = (const float*)(sm + POOLF);
    float s0 = 0.f, s1 = 0.f, s2 = 0.f, s3 = 0.f;
#pragma unroll 4
    for (int kk = 0; kk < 48; kk += 4){
      int k = wv*48 + kk;
      s0 = fmaf(pool[k+0], roW[(size_t)(k+0)*64 + lane], s0);
      s1 = fmaf(pool[k+1], roW[(size_t)(k+1)*64 + lane], s1);
      s2 = fmaf(pool[k+2], roW[(size_t)(k+2)*64 + lane], s2);
      s3 = fmaf(pool[k+3], roW[(size_t)(k+3)*64 + lane], s3);
    }
    atomicAdd((float*)(sm + RACC) + lane, (s0+s1) + (s2+s3));
  }
  __syncthreads();
  // ---- P9: readout LN (wave 0) ----
  if (wv == 0){
    float v = ((float*)(sm + RACC))[lane] + rob[lane];
    float mu = red64(v) * 0.015625f;
    float d = v - mu;
    float var = red64(d*d) * 0.015625f;
    float y = fmaf(d * rsqrtf(var + 1e-5f), rog[lane], robe[lane]);
    out[(size_t)b*64 + lane] = fmaxf(y, 0.f);
  }
}

extern "C" void kernel_launch(void* const* d_in, const int* in_sizes, int n_in,
                              void* d_out, int out_size, void* d_ws, size_t ws_size,
                              hipStream_t stream) {
  const float* tile = (const float*)d_in[0];
  const int* h2v  = (const int*)d_in[1];
  const int* v2h  = (const int*)d_in[2];
  const int* e2v  = (const int*)d_in[3];
  const int* v2e  = (const int*)d_in[4];
  const float* hinW = (const float*)d_in[5];
  const float* hinb = (const float*)d_in[6];
  const float* hing = (const float*)d_in[7];
  const float* hinbe= (const float*)d_in[8];
  const float* vinW = (const float*)d_in[9];
  const float* vinb = (const float*)d_in[10];
  const float* ving = (const float*)d_in[11];
  const float* vinbe= (const float*)d_in[12];
  const float* einW = (const float*)d_in[13];
  const float* einb = (const float*)d_in[14];
  const float* eing = (const float*)d_in[15];
  const float* einbe= (const float*)d_in[16];
  const float* huW  = (const float*)d_in[17];
  const float* hub  = (const float*)d_in[18];
  const float* hug  = (const float*)d_in[19];
  const float* hube = (const float*)d_in[20];
  const float* vuW  = (const float*)d_in[21];
  const float* vub  = (const float*)d_in[22];
  const float* vug  = (const float*)d_in[23];
  const float* vube = (const float*)d_in[24];
  const float* euW  = (const float*)d_in[25];
  const float* eub  = (const float*)d_in[26];
  const float* eug  = (const float*)d_in[27];
  const float* eube = (const float*)d_in[28];
  const float* roW  = (const float*)d_in[29];
  const float* rob  = (const float*)d_in[30];
  const float* rog  = (const float*)d_in[31];
  const float* robe = (const float*)d_in[32];
  float* out = (float*)d_out;

  int B = in_sizes[0] / 608;   // 16384
  hipLaunchKernelGGL(graph_enc_kernel, dim3(B), dim3(BLK), 0, stream,
      tile, h2v, v2h, e2v, v2e,
      hinW, hinb, hing, hinbe,
      vinW, vinb, ving, vinbe,
      einW, einb, eing, einbe,
      huW, hub, hug, hube,
      vuW, vub, vug, vube,
      euW, eub, eug, eube,
      roW, rob, rog, robe,
      out);
}

// Round 5
// 3143.141 us; speedup vs baseline: 2.3782x; 1.2467x over previous
//
#include <hip/hip_runtime.h>

// Fused per-batch graph encoder, v5: MFMA bf16 + pre-packed weights.
// Prep kernel packs all W into d_ws as bf16 in MFMA B-fragment lane order
// (1KB frag-blocks); main kernel B-frag = one coalesced dwordx4 load (L2-hot).
// 512 threads (8 waves)/block, 48KB LDS, amdgpu_waves_per_eu(4,4) -> 128 VGPR
// budget, no spills. acts/gathers bf16 in LDS, XOR-swizzled (conflict-free
// ds_read_b64 fragment loads). Each wave owns 1-2 16-row output tiles
// end-to-end: MFMA acc in regs -> 16-lane shfl LN -> bf16 writeback.

#define BLK 512

typedef short v4s __attribute__((ext_vector_type(4)));
typedef short v8s __attribute__((ext_vector_type(8)));
typedef float v4f __attribute__((ext_vector_type(4)));

// byte offsets into the 49152-B shared block
#define ACTS    0              // 160 rows x 64 col bf16, stride 128, swz mask 15
#define GATA    20480          // 145+ rows x 64 (h_from_v / v_from_h / e_from_v)
#define GATB    40960          // 54 rows x 64 (v_from_e)
// stage-0 overlays (GATA/GATB free until the rounds)
#define S0TILEF (GATA + 0)     // 19x32 f32, plain
#define S0VRAWF (GATA + 2432)  // 54x32 f32, plain
#define S0TILEB (GATA + 9344)  // 32x32 bf16, stride 64, swz mask 7
#define S0VRAWB (GATA + 11392) // 64x32 bf16
#define S0ERAWB (GATB + 0)     // 72x32 bf16
// post-round overlays (gathers dead by then)
#define POOLF   (GATB + 6144)  // 192 f32
#define RACC    (GATB + 6912)  // 64 f32

// packed-W frag-block bases (1 block = 64 lanes x 8 bf16 = 1KB)
#define FB_HIN 0
#define FB_VIN 4
#define FB_EIN 8
#define FB_HU  12   // +16 per round
#define FB_VU  44   // +24 per round
#define FB_EU  92   // +16 per round
#define NFB    124

__device__ __forceinline__ unsigned short f2bf(float f){
  unsigned u = __float_as_uint(f);
  return (unsigned short)((u + 0x7fffu + ((u >> 16) & 1u)) >> 16);
}
__device__ __forceinline__ float bf2f(unsigned short h){
  return __uint_as_float(((unsigned)h) << 16);
}

__device__ __forceinline__ float red16(float v){
  v += __shfl_xor(v, 1, 64);
  v += __shfl_xor(v, 2, 64);
  v += __shfl_xor(v, 4, 64);
  v += __shfl_xor(v, 8, 64);
  return v;
}
__device__ __forceinline__ float red64(float v){
#pragma unroll
  for (int m = 32; m >= 1; m >>= 1) v += __shfl_xor(v, m, 64);
  return v;
}

__device__ __forceinline__ int swz_off(int base, int stride, int row, int col, int m){
  return base + row*stride + ((((col >> 2) ^ (row & m)) << 3) + ((col & 3) << 1));
}
__device__ __forceinline__ unsigned short lds_bf_read(const unsigned char* sm, int base, int stride, int row, int col, int m){
  return *(const unsigned short*)(sm + swz_off(base, stride, row, col, m));
}
__device__ __forceinline__ void lds_bf_write(unsigned char* sm, int base, int stride, int row, int col, int m, unsigned short v){
  *(unsigned short*)(sm + swz_off(base, stride, row, col, m)) = v;
}

// A-fragment: lane l row=(l&15), k(j) = 32*seg + 16*(j>>2) + 4*(l>>4) + (j&3).
__device__ __forceinline__ v8s load_frag(const unsigned char* sm, int base, int stride, int row, int cb, int m){
  v4s lo = *(const v4s*)(sm + base + row*stride + (((cb    ) ^ (row & m)) << 3));
  v4s hi = *(const v4s*)(sm + base + row*stride + (((cb + 4) ^ (row & m)) << 3));
  v8s r; r[0]=lo[0]; r[1]=lo[1]; r[2]=lo[2]; r[3]=lo[3]; r[4]=hi[0]; r[5]=hi[1]; r[6]=hi[2]; r[7]=hi[3];
  return r;
}

// TYPE: 0=hex 1=vtx 2=edge. S0: stage-0 (K=32). wp = packed frag base for matrix.
template<int TYPE, bool S0>
__device__ __forceinline__ void tile_accum(const unsigned char* sm, int roff, int lane,
                                           const v8s* __restrict__ wp, v4f acc[4])
{
  constexpr int NSEG = S0 ? 1 : (TYPE == 1 ? 6 : 4);
  constexpr int STR  = S0 ? 64 : 128;
  constexpr int MSK  = S0 ? 7  : 15;
  const int m15 = lane & 15, g = lane >> 4;
#pragma unroll
  for (int s = 0; s < NSEG; ++s){
    int buf, rb, kb;
    if constexpr (S0){
      buf = (TYPE==0 ? S0TILEB : (TYPE==1 ? S0VRAWB : S0ERAWB)); rb = 0; kb = 0;
    } else {
      kb = s & 1;
      int ab = (TYPE==0 ? 0 : (TYPE==1 ? 19 : 73));
      if (s < 2)      { buf = ACTS; rb = ab; }
      else if (s < 4) { buf = GATA; rb = ab; }
      else            { buf = GATB; rb = 0;  }
    }
    v8s af = load_frag(sm, buf, STR, rb + roff + m15, kb*8 + g, MSK);
#pragma unroll
    for (int nt = 0; nt < 4; ++nt){
      v8s bf = wp[(s*4 + nt)*64 + lane];
      acc[nt] = __builtin_amdgcn_mfma_f32_16x16x32_bf16(af, bf, acc[nt], 0, 0, 0);
    }
  }
}

// LN+ReLU a 16-row tile (C layout: col=l&15, row=4*(l>>4)+q), write bf16 acts.
__device__ __forceinline__ void tile_ln_store(unsigned char* sm, int typeRow0, int Mv, int roff, int lane,
    const float* __restrict__ bp, const float* __restrict__ gp, const float* __restrict__ bep, v4f acc[4])
{
  int c0 = lane & 15, g4 = (lane >> 4) << 2;
  float bb[4], gg[4], ee[4];
#pragma unroll
  for (int nt = 0; nt < 4; ++nt){
    int col = nt*16 + c0;
    bb[nt] = bp[col]; gg[nt] = gp[col]; ee[nt] = bep[col];
  }
#pragma unroll
  for (int nt = 0; nt < 4; ++nt)
#pragma unroll
    for (int q = 0; q < 4; ++q) acc[nt][q] += bb[nt];
#pragma unroll
  for (int q = 0; q < 4; ++q){
    float s  = acc[0][q] + acc[1][q] + acc[2][q] + acc[3][q];
    float mu = red16(s) * 0.015625f;
    float d0 = acc[0][q]-mu, d1 = acc[1][q]-mu, d2 = acc[2][q]-mu, d3 = acc[3][q]-mu;
    float var = red16(d0*d0 + d1*d1 + d2*d2 + d3*d3) * 0.015625f;
    float rs = rsqrtf(var + 1e-5f);
    int row = roff + g4 + q;
    if (row < Mv){
      float y0 = fmaxf(fmaf(d0*rs, gg[0], ee[0]), 0.f);
      float y1 = fmaxf(fmaf(d1*rs, gg[1], ee[1]), 0.f);
      float y2 = fmaxf(fmaf(d2*rs, gg[2], ee[2]), 0.f);
      float y3 = fmaxf(fmaf(d3*rs, gg[3], ee[3]), 0.f);
      lds_bf_write(sm, ACTS, 128, typeRow0+row,  0+c0, 15, f2bf(y0));
      lds_bf_write(sm, ACTS, 128, typeRow0+row, 16+c0, 15, f2bf(y1));
      lds_bf_write(sm, ACTS, 128, typeRow0+row, 32+c0, 15, f2bf(y2));
      lds_bf_write(sm, ACTS, 128, typeRow0+row, 48+c0, 15, f2bf(y3));
    }
  }
}

// ---- prep kernel: pack all W (f32, K x 64) into bf16 B-fragment order ----
__global__ void pack_w_kernel(
    const float* __restrict__ hinW, const float* __restrict__ vinW,
    const float* __restrict__ einW, const float* __restrict__ huW,
    const float* __restrict__ vuW,  const float* __restrict__ euW,
    unsigned short* __restrict__ wp)
{
  int fb = blockIdx.x, l = threadIdx.x;
  const float* W; int s, nt;
  if (fb < 8){
    if (fb < 4){ W = hinW; s = 0; nt = fb; }
    else       { W = vinW; s = 0; nt = fb - 4; }
  } else if (fb < 12){ W = einW; s = 0; nt = fb - 8; }
  else if (fb < 44){ int t = fb - 12; W = huW + (t >> 4)*8192;  int rem = t & 15; s = rem >> 2; nt = rem & 3; }
  else if (fb < 92){ int t = fb - 44; W = vuW + (t / 24)*12288; int rem = t % 24; s = rem >> 2; nt = rem & 3; }
  else             { int t = fb - 92; W = euW + (t >> 4)*8192;  int rem = t & 15; s = rem >> 2; nt = rem & 3; }
  int g4 = (l >> 4) << 2, col = nt*16 + (l & 15);
  unsigned short* dst = wp + ((size_t)fb*64 + l)*8;
#pragma unroll
  for (int j = 0; j < 8; ++j){
    int k = s*32 + ((j >> 2) << 4) + g4 + (j & 3);
    dst[j] = f2bf(W[k*64 + col]);
  }
}

__global__ __launch_bounds__(BLK) __attribute__((amdgpu_waves_per_eu(4,4)))
void graph_enc_kernel(
    const float* __restrict__ tile,
    const int* __restrict__ h2v, const int* __restrict__ v2h,
    const int* __restrict__ e2v, const int* __restrict__ v2e,
    const v8s* __restrict__ wpack,
    const float* __restrict__ hinb, const float* __restrict__ hing, const float* __restrict__ hinbe,
    const float* __restrict__ vinb, const float* __restrict__ ving, const float* __restrict__ vinbe,
    const float* __restrict__ einb, const float* __restrict__ eing, const float* __restrict__ einbe,
    const float* __restrict__ hub,  const float* __restrict__ hug,  const float* __restrict__ hube,
    const float* __restrict__ vub,  const float* __restrict__ vug,  const float* __restrict__ vube,
    const float* __restrict__ eub,  const float* __restrict__ eug,  const float* __restrict__ eube,
    const float* __restrict__ roW,  const float* __restrict__ rob,
    const float* __restrict__ rog,  const float* __restrict__ robe,
    float* __restrict__ out)
{
  __shared__ __align__(16) unsigned char sm[49152];
  const int b = blockIdx.x, t = threadIdx.x, lane = t & 63, wv = t >> 6;

  // ---- P0: stage tile features (f32 plain + bf16 swizzled) ----
  const float* tsrc = tile + (size_t)b * 608;
  float* tilef = (float*)(sm + S0TILEF);
  for (int i = t; i < 608; i += BLK){
    float f = tsrc[i];
    tilef[i] = f;
    lds_bf_write(sm, S0TILEB, 64, i >> 5, i & 31, 7, f2bf(f));
  }
  __syncthreads();
  // ---- P1: vertex_raw ----
  {
    float* vrawf = (float*)(sm + S0VRAWF);
    int hr = t >> 5, c = t & 31;
    for (int v = hr; v < 54; v += 16){
      float s = 0.f; int cnt = 0;
#pragma unroll
      for (int j = 0; j < 3; ++j){ int ix = v2h[v*3+j]; if (ix >= 0){ s += tilef[ix*32 + c]; cnt++; } }
      float mval = s / (float)(cnt > 0 ? cnt : 1);
      vrawf[v*32 + c] = mval;
      lds_bf_write(sm, S0VRAWB, 64, v, c, 7, f2bf(mval));
    }
  }
  __syncthreads();
  // ---- P2: edge_raw ----
  {
    const float* vrawf = (const float*)(sm + S0VRAWF);
    int hr = t >> 5, c = t & 31;
    for (int e = hr; e < 72; e += 16){
      float s = 0.f; int cnt = 0;
#pragma unroll
      for (int j = 0; j < 2; ++j){ int ix = e2v[e*2+j]; if (ix >= 0){ s += vrawf[ix*32 + c]; cnt++; } }
      float mval = s / (float)(cnt > 0 ? cnt : 1);
      lds_bf_write(sm, S0ERAWB, 64, e, c, 7, f2bf(mval));
    }
  }
  __syncthreads();

  v4f z; z[0]=0.f; z[1]=0.f; z[2]=0.f; z[3]=0.f;

  // ---- P3: stage-0 GEMMs (K=32) + LN ----
  {
    const v8s* hinP = wpack + FB_HIN*64;
    const v8s* vinP = wpack + FB_VIN*64;
    const v8s* einP = wpack + FB_EIN*64;
    v4f a0[4] = {z,z,z,z}, a1[4] = {z,z,z,z};
    switch (wv){
      case 0: tile_accum<0,true>(sm, 0,lane,hinP,a0); tile_accum<0,true>(sm,16,lane,hinP,a1); break;
      case 1: tile_accum<1,true>(sm, 0,lane,vinP,a0); break;
      case 2: tile_accum<1,true>(sm,16,lane,vinP,a0); break;
      case 3: tile_accum<1,true>(sm,32,lane,vinP,a0); break;
      case 4: tile_accum<1,true>(sm,48,lane,vinP,a0); break;
      case 5: tile_accum<2,true>(sm, 0,lane,einP,a0); tile_accum<2,true>(sm,64,lane,einP,a1); break;
      case 6: tile_accum<2,true>(sm,16,lane,einP,a0); tile_accum<2,true>(sm,48,lane,einP,a1); break;
      case 7: tile_accum<2,true>(sm,32,lane,einP,a0); break;
    }
    __syncthreads();
    switch (wv){
      case 0: tile_ln_store(sm, 0,19, 0,lane,hinb,hing,hinbe,a0); tile_ln_store(sm, 0,19,16,lane,hinb,hing,hinbe,a1); break;
      case 1: tile_ln_store(sm,19,54, 0,lane,vinb,ving,vinbe,a0); break;
      case 2: tile_ln_store(sm,19,54,16,lane,vinb,ving,vinbe,a0); break;
      case 3: tile_ln_store(sm,19,54,32,lane,vinb,ving,vinbe,a0); break;
      case 4: tile_ln_store(sm,19,54,48,lane,vinb,ving,vinbe,a0); break;
      case 5: tile_ln_store(sm,73,72, 0,lane,einb,eing,einbe,a0); tile_ln_store(sm,73,72,64,lane,einb,eing,einbe,a1); break;
      case 6: tile_ln_store(sm,73,72,16,lane,einb,eing,einbe,a0); tile_ln_store(sm,73,72,48,lane,einb,eing,einbe,a1); break;
      case 7: tile_ln_store(sm,73,72,32,lane,einb,eing,einbe,a0); break;
    }
  }
  __syncthreads();

  // ---- 2 message-passing rounds ----
  for (int r = 0; r < 2; ++r){
    // P4: gathers (199 rows, wave-strided) from old acts
    for (int gid = wv; gid < 199; gid += 8){
      const int* idx; int deg, srcB, dbase, drow;
      if (gid < 19)      { idx = h2v + gid*6;        deg = 6; srcB = 19; dbase = GATA; drow = gid; }
      else if (gid < 73) { int v = gid-19;  idx = v2h + v*3; deg = 3; srcB = 0;  dbase = GATA; drow = 19+v; }
      else if (gid < 145){ int e = gid-73;  idx = e2v + e*2; deg = 2; srcB = 19; dbase = GATA; drow = 73+e; }
      else               { int v = gid-145; idx = v2e + v*3; deg = 3; srcB = 73; dbase = GATB; drow = v; }
      float s = 0.f; int cnt = 0;
      for (int j = 0; j < deg; ++j){
        int ix = idx[j];
        if (ix >= 0){ s += bf2f(lds_bf_read(sm, ACTS, 128, srcB+ix, lane, 15)); cnt++; }
      }
      float mval = s / (float)(cnt > 0 ? cnt : 1);
      lds_bf_write(sm, dbase, 128, drow, lane, 15, f2bf(mval));
    }
    __syncthreads();
    // P5: GEMM accumulate (reads old acts + gathers; no LDS writes)
    const v8s* huP = wpack + (FB_HU + r*16)*64;
    const v8s* vuP = wpack + (FB_VU + r*24)*64;
    const v8s* euP = wpack + (FB_EU + r*16)*64;
    v4f a0[4] = {z,z,z,z}, a1[4] = {z,z,z,z};
    switch (wv){
      case 0: tile_accum<0,false>(sm, 0,lane,huP,a0); tile_accum<0,false>(sm,16,lane,huP,a1); break;
      case 1: tile_accum<1,false>(sm, 0,lane,vuP,a0); break;
      case 2: tile_accum<1,false>(sm,16,lane,vuP,a0); break;
      case 3: tile_accum<1,false>(sm,32,lane,vuP,a0); break;
      case 4: tile_accum<1,false>(sm,48,lane,vuP,a0); break;
      case 5: tile_accum<2,false>(sm, 0,lane,euP,a0); tile_accum<2,false>(sm,64,lane,euP,a1); break;
      case 6: tile_accum<2,false>(sm,16,lane,euP,a0); tile_accum<2,false>(sm,48,lane,euP,a1); break;
      case 7: tile_accum<2,false>(sm,32,lane,euP,a0); break;
    }
    __syncthreads();
    // P6: LN + writeback
    const float *hub_r = hub + r*64, *hug_r = hug + r*64, *hube_r = hube + r*64;
    const float *vub_r = vub + r*64, *vug_r = vug + r*64, *vube_r = vube + r*64;
    const float *eub_r = eub + r*64, *eug_r = eug + r*64, *eube_r = eube + r*64;
    switch (wv){
      case 0: tile_ln_store(sm, 0,19, 0,lane,hub_r,hug_r,hube_r,a0); tile_ln_store(sm, 0,19,16,lane,hub_r,hug_r,hube_r,a1); break;
      case 1: tile_ln_store(sm,19,54, 0,lane,vub_r,vug_r,vube_r,a0); break;
      case 2: tile_ln_store(sm,19,54,16,lane,vub_r,vug_r,vube_r,a0); break;
      case 3: tile_ln_store(sm,19,54,32,lane,vub_r,vug_r,vube_r,a0); break;
      case 4: tile_ln_store(sm,19,54,48,lane,vub_r,vug_r,vube_r,a0); break;
      case 5: tile_ln_store(sm,73,72, 0,lane,eub_r,eug_r,eube_r,a0); tile_ln_store(sm,73,72,64,lane,eub_r,eug_r,eube_r,a1); break;
      case 6: tile_ln_store(sm,73,72,16,lane,eub_r,eug_r,eube_r,a0); tile_ln_store(sm,73,72,48,lane,eub_r,eug_r,eube_r,a1); break;
      case 7: tile_ln_store(sm,73,72,32,lane,eub_r,eug_r,eube_r,a0); break;
    }
    __syncthreads();
  }

  // ---- P7: pooling (waves 0-2) + zero readout acc (wave 3) ----
  if (wv < 3){
    int R  = (wv == 0 ? 19 : (wv == 1 ? 54 : 72));
    int B0 = (wv == 0 ? 0  : (wv == 1 ? 19 : 73));
    float s = 0.f;
    for (int n = 0; n < R; ++n) s += bf2f(lds_bf_read(sm, ACTS, 128, B0+n, lane, 15));
    ((float*)(sm + POOLF))[wv*64 + lane] = s / (float)R;
  } else if (wv == 3){
    ((float*)(sm + RACC))[lane] = 0.f;
  }
  __syncthreads();
  // ---- P8: readout partials (waves 0-3, 48 K each) ----
  if (wv < 4){
    const float* pool = (const float*)(sm + POOLF);
    float s0 = 0.f, s1 = 0.f, s2 = 0.f, s3 = 0.f;
#pragma unroll 4
    for (int kk = 0; kk < 48; kk += 4){
      int k = wv*48 + kk;
      s0 = fmaf(pool[k+0], roW[(size_t)(k+0)*64 + lane], s0);
      s1 = fmaf(pool[k+1], roW[(size_t)(k+1)*64 + lane], s1);
      s2 = fmaf(pool[k+2], roW[(size_t)(k+2)*64 + lane], s2);
      s3 = fmaf(pool[k+3], roW[(size_t)(k+3)*64 + lane], s3);
    }
    atomicAdd((float*)(sm + RACC) + lane, (s0+s1) + (s2+s3));
  }
  __syncthreads();
  // ---- P9: readout LN (wave 0) ----
  if (wv == 0){
    float v = ((float*)(sm + RACC))[lane] + rob[lane];
    float mu = red64(v) * 0.015625f;
    float d = v - mu;
    float var = red64(d*d) * 0.015625f;
    float y = fmaf(d * rsqrtf(var + 1e-5f), rog[lane], robe[lane]);
    out[(size_t)b*64 + lane] = fmaxf(y, 0.f);
  }
}

extern "C" void kernel_launch(void* const* d_in, const int* in_sizes, int n_in,
                              void* d_out, int out_size, void* d_ws, size_t ws_size,
                              hipStream_t stream) {
  const float* tile = (const float*)d_in[0];
  const int* h2v  = (const int*)d_in[1];
  const int* v2h  = (const int*)d_in[2];
  const int* e2v  = (const int*)d_in[3];
  const int* v2e  = (const int*)d_in[4];
  const float* hinW = (const float*)d_in[5];
  const float* hinb = (const float*)d_in[6];
  const float* hing = (const float*)d_in[7];
  const float* hinbe= (const float*)d_in[8];
  const float* vinW = (const float*)d_in[9];
  const float* vinb = (const float*)d_in[10];
  const float* ving = (const float*)d_in[11];
  const float* vinbe= (const float*)d_in[12];
  const float* einW = (const float*)d_in[13];
  const float* einb = (const float*)d_in[14];
  const float* eing = (const float*)d_in[15];
  const float* einbe= (const float*)d_in[16];
  const float* huW  = (const float*)d_in[17];
  const float* hub  = (const float*)d_in[18];
  const float* hug  = (const float*)d_in[19];
  const float* hube = (const float*)d_in[20];
  const float* vuW  = (const float*)d_in[21];
  const float* vub  = (const float*)d_in[22];
  const float* vug  = (const float*)d_in[23];
  const float* vube = (const float*)d_in[24];
  const float* euW  = (const float*)d_in[25];
  const float* eub  = (const float*)d_in[26];
  const float* eug  = (const float*)d_in[27];
  const float* eube = (const float*)d_in[28];
  const float* roW  = (const float*)d_in[29];
  const float* rob  = (const float*)d_in[30];
  const float* rog  = (const float*)d_in[31];
  const float* robe = (const float*)d_in[32];
  float* out = (float*)d_out;

  unsigned short* wpack = (unsigned short*)d_ws;   // 124 KB used

  hipLaunchKernelGGL(pack_w_kernel, dim3(NFB), dim3(64), 0, stream,
      hinW, vinW, einW, huW, vuW, euW, wpack);

  int B = in_sizes[0] / 608;   // 16384
  hipLaunchKernelGGL(graph_enc_kernel, dim3(B), dim3(BLK), 0, stream,
      tile, h2v, v2h, e2v, v2e,
      (const v8s*)wpack,
      hinb, hing, hinbe,
      vinb, ving, vinbe,
      einb, eing, einbe,
      hub, hug, hube,
      vub, vug, vube,
      eub, eug, eube,
      roW, rob, rog, robe,
      out);
}